// Round 2
// baseline (152.501 us; speedup 1.0000x reference)
//
#include <hip/hip_runtime.h>

#define B_  8
#define D_  1024
#define G_  32
#define K_  64
#define NP_ 1024

// ws layout (floats):
//   wc : [0, B*G*K)            = 16384   weights*coeff*mask (0 => skip column)
//   xr : [16384, 32768)                  xopt-rotation per (b,g,l)
//   rt : [32768, 36864)                  R transposed: rt[l*K + k] = R[k*K + l]

__global__ void prep_rt(const float* __restrict__ R, float* __restrict__ rt) {
  int l = blockIdx.x;
  int k = threadIdx.x;
  rt[l * K_ + k] = R[k * K_ + l];
}

__global__ void prep_bg(const float* __restrict__ weights,
                        const float* __restrict__ xopt,
                        const float* __restrict__ R,
                        const int* __restrict__ gidx,
                        const int* __restrict__ mask,     // numpy bool -> int32 in harness
                        const int* __restrict__ counts,
                        float* __restrict__ wc,
                        float* __restrict__ xr) {
  int bg = blockIdx.x;          // b*G + g
  int b  = bg / G_;
  int g  = bg % G_;
  int l  = threadIdx.x;

  float w   = weights[bg];
  int   cnt = counts[b];
  const float LOG2_1E6 = 19.931568569324174f;
  float coeff = exp2f((float)l * (LOG2_1E6 / 63.0f));
  bool valid = (g < cnt) && (mask[bg * K_ + l] != 0);
  wc[bg * K_ + l] = valid ? (w * coeff) : 0.0f;

  // xr[b,g,l] = sum_k xopt[b, idx[b,g,k]] * R[k][l]
  float acc = 0.0f;
  const int*   gi = gidx + bg * K_;
  const float* xb = xopt + b * D_;
#pragma unroll
  for (int k = 0; k < K_; ++k) {
    acc = fmaf(xb[gi[k]], R[k * K_ + l], acc);
  }
  xr[bg * K_ + l] = acc;
}

__global__ __launch_bounds__(64) void fitness_kernel(
    const float* __restrict__ x,
    const int* __restrict__ gidx,
    const int* __restrict__ counts,
    const float* __restrict__ wc,
    const float* __restrict__ xr,
    const float* __restrict__ rt,
    float* __restrict__ out) {
  const int t = blockIdx.x;   // n-tile (16)
  const int g = blockIdx.y;   // group (32)
  const int b = blockIdx.z;   // batch (8)

  if (g >= counts[b]) return;                  // group_valid skip (wave-uniform)

  const int lane = threadIdx.x;
  const int n    = t * 64 + lane;
  const int bg   = b * G_ + g;

  const int*   gi   = gidx + bg * K_;
  const float* xrow = x + ((size_t)(b * NP_ + n)) * D_;

  // Gather this lane's 64 sub-vector elements (xopt handled via xr).
  float zs[K_];
#pragma unroll
  for (int k = 0; k < K_; ++k) {
    zs[k] = xrow[gi[k]];
  }

  const float*  wcl = wc + bg * K_;
  const float*  xrl = xr + bg * K_;
  float fit = 0.0f;

  for (int l = 0; l < K_; ++l) {
    float w = wcl[l];
    if (w != 0.0f) {                           // masked column skip (wave-uniform)
      const float4* rr4 = (const float4*)(rt + l * K_);
      float s0 = 0.f, s1 = 0.f, s2 = 0.f, s3 = 0.f;
#pragma unroll
      for (int q = 0; q < K_ / 4; ++q) {
        float4 r = rr4[q];
        s0 = fmaf(zs[4 * q + 0], r.x, s0);
        s1 = fmaf(zs[4 * q + 1], r.y, s1);
        s2 = fmaf(zs[4 * q + 2], r.z, s2);
        s3 = fmaf(zs[4 * q + 3], r.w, s3);
      }
      float s = (s0 + s1) + (s2 + s3);
      s -= xrl[l];                             // subtract xopt·R (uniform)
      fit = fmaf(w, s * s, fit);
    }
  }

  atomicAdd(out + b * NP_ + n, fit);
}

extern "C" void kernel_launch(void* const* d_in, const int* in_sizes, int n_in,
                              void* d_out, int out_size, void* d_ws, size_t ws_size,
                              hipStream_t stream) {
  const float* x       = (const float*)d_in[0];   // (B,NP,D)
  const float* weights = (const float*)d_in[1];   // (B,G)
  const float* xopt    = (const float*)d_in[2];   // (B,D)
  const float* R       = (const float*)d_in[3];   // (K,K)
  const int*   gidx    = (const int*)d_in[4];     // (B,G,K)
  const int*   mask    = (const int*)d_in[5];     // (B,G,K) bool -> int32
  const int*   counts  = (const int*)d_in[6];     // (B,)
  float*       out     = (float*)d_out;           // (B,NP)

  float* wc = (float*)d_ws;
  float* xr = wc + B_ * G_ * K_;
  float* rt = xr + B_ * G_ * K_;

  // out is re-poisoned before every timed launch; we accumulate with atomics.
  hipMemsetAsync(d_out, 0, (size_t)out_size * sizeof(float), stream);

  prep_rt<<<dim3(K_), dim3(K_), 0, stream>>>(R, rt);
  prep_bg<<<dim3(B_ * G_), dim3(K_), 0, stream>>>(weights, xopt, R, gidx, mask,
                                                  counts, wc, xr);

  fitness_kernel<<<dim3(NP_ / 64, G_, B_), dim3(64), 0, stream>>>(
      x, gidx, counts, wc, xr, rt, out);
}

// Round 3
// 126.485 us; speedup vs baseline: 1.2057x; 1.2057x over previous
//
#include <hip/hip_runtime.h>
#include <hip/hip_fp16.h>

#define B_     8
#define D_     1024
#define G_     32
#define K_     64
#define NP_    1024
#define ROWS   32
#define TPB    512            // 8 waves
#define STRIDE 1026           // halfs per LDS row: 1024 + 2 pad -> bank = (row + gi/2)%32, 2-way = free

// ws: wc[B*G*K] floats, then rt[K*K] floats
__global__ void prep(const float* __restrict__ weights,
                     const int* __restrict__ mask,
                     const int* __restrict__ counts,
                     const float* __restrict__ R,
                     float* __restrict__ wc,
                     float* __restrict__ rt) {
  int idx = blockIdx.x * 256 + threadIdx.x;      // 0..16383
  int bg = idx >> 6, l = idx & 63;
  int b = bg >> 5, g = bg & 31;
  const float C = 19.931568569324174f / 63.0f;   // log2(1e6)/63
  float coeff = exp2f((float)l * C);
  bool valid = (g < counts[b]) && (mask[idx] != 0);
  wc[idx] = valid ? weights[bg] * coeff : 0.0f;
  if (idx < K_ * K_) rt[idx] = R[(idx & 63) * K_ + (idx >> 6)];  // rt[l][k] = R[k][l]
}

__global__ __launch_bounds__(TPB, 2) void fitness(
    const float* __restrict__ x,
    const float* __restrict__ xopt,
    const int* __restrict__ gidx,
    const int* __restrict__ counts,
    const float* __restrict__ wc,
    const float* __restrict__ rt,
    float* __restrict__ out) {
  __shared__ __half zh[ROWS * STRIDE];           // 65.7 KB
  __shared__ float red[8][64];                   // per-wave partials

  const int tile = blockIdx.x;                   // 0..31
  const int b    = blockIdx.y;                   // 0..7
  const int t    = threadIdx.x;

  // ---- stage z = x - xopt as fp16, coalesced float4 ----
  {
    const float4* x4  = (const float4*)(x + ((size_t)(b * NP_ + tile * ROWS)) * D_);
    const float4* xo4 = (const float4*)(xopt + b * D_);
    const int col4 = t & 255;                    // invariant across j
    float4 xo = xo4[col4];
    for (int j = 0; j < (ROWS * 256) / TPB; ++j) {   // 16 iters
      int chunk = t + TPB * j;
      int row = chunk >> 8;
      float4 xv = x4[row * 256 + col4];
      __half2 h01 = __floats2half2_rn(xv.x - xo.x, xv.y - xo.y);
      __half2 h23 = __floats2half2_rn(xv.z - xo.z, xv.w - xo.w);
      __half2* p = (__half2*)(zh + row * STRIDE + col4 * 4);
      p[0] = h01;
      p[1] = h23;
    }
  }
  __syncthreads();

  // ---- compute: wave w handles g-pairs p = w, w+8, ...; half-wave h takes g = 2p+h ----
  const int wv   = __builtin_amdgcn_readfirstlane(t >> 6);  // force wave-uniform
  const int lane = t & 63;
  const int row  = lane & 31;
  const int h    = lane >> 5;
  const int cnt  = counts[b];

  const __half* myrow = zh + row * STRIDE;
  float fit = 0.0f;

  for (int p = wv; 2 * p < cnt; p += 8) {
    const int bg0 = b * G_ + 2 * p;
    const int* gi_h = gidx + (bg0 + h) * K_;     // per-lane (2 addrs/wave), L1-hot
    float zs[K_];
#pragma unroll
    for (int k = 0; k < K_; ++k) {
      zs[k] = __half2float(myrow[gi_h[k]]);      // ds_read_u16, 2-way banks = free
    }
    const float* wch = wc + (bg0 + h) * K_;
    for (int l = 0; l < K_; ++l) {
      float wl = wch[l];
      if (__any(wl != 0.0f)) {                   // uniform skip (~25% of l all-zero)
        const float* rl = rt + l * K_;           // wave-uniform -> s_load
        float s0 = 0.f, s1 = 0.f, s2 = 0.f, s3 = 0.f;
#pragma unroll
        for (int q = 0; q < K_ / 4; ++q) {
          s0 = fmaf(zs[4 * q + 0], rl[4 * q + 0], s0);
          s1 = fmaf(zs[4 * q + 1], rl[4 * q + 1], s1);
          s2 = fmaf(zs[4 * q + 2], rl[4 * q + 2], s2);
          s3 = fmaf(zs[4 * q + 3], rl[4 * q + 3], s3);
        }
        float s = (s0 + s1) + (s2 + s3);
        fit = fmaf(wl, s * s, fit);
      }
    }
  }

  red[wv][lane] = fit;
  __syncthreads();

  // ---- reduce 8 waves x 2 halves per row, plain store (no atomics/memset) ----
  if (t < ROWS) {
    float s = 0.0f;
#pragma unroll
    for (int w2 = 0; w2 < 8; ++w2) s += red[w2][t] + red[w2][t + 32];
    out[b * NP_ + tile * ROWS + t] = s;
  }
}

extern "C" void kernel_launch(void* const* d_in, const int* in_sizes, int n_in,
                              void* d_out, int out_size, void* d_ws, size_t ws_size,
                              hipStream_t stream) {
  const float* x       = (const float*)d_in[0];   // (B,NP,D)
  const float* weights = (const float*)d_in[1];   // (B,G)
  const float* xopt    = (const float*)d_in[2];   // (B,D)
  const float* R       = (const float*)d_in[3];   // (K,K)
  const int*   gidx    = (const int*)d_in[4];     // (B,G,K)
  const int*   mask    = (const int*)d_in[5];     // (B,G,K) bool -> int32
  const int*   counts  = (const int*)d_in[6];     // (B,)
  float*       out     = (float*)d_out;           // (B,NP)

  float* wc = (float*)d_ws;                       // 16384 floats
  float* rt = wc + B_ * G_ * K_;                  // 4096 floats

  prep<<<dim3(64), dim3(256), 0, stream>>>(weights, mask, counts, R, wc, rt);
  fitness<<<dim3(NP_ / ROWS, B_), dim3(TPB), 0, stream>>>(
      x, xopt, gidx, counts, wc, rt, out);
}

// Round 4
// 107.453 us; speedup vs baseline: 1.4192x; 1.1771x over previous
//
#include <hip/hip_runtime.h>
#include <hip/hip_fp16.h>

#define B_     8
#define D_     1024
#define G_     32
#define K_     64
#define NP_    1024
#define ROWS   32
#define TPB    1024           // 16 waves
#define STRIDE 1026           // halfs per LDS row (pad 2)

__global__ __launch_bounds__(TPB, 4) void fitness(
    const float* __restrict__ x,
    const float* __restrict__ weights,
    const float* __restrict__ xopt,
    const float* __restrict__ R,
    const int* __restrict__ gidx,
    const int* __restrict__ mask,     // numpy bool -> int32
    const int* __restrict__ counts,
    float* __restrict__ out) {
  __shared__ __half zh[ROWS * STRIDE];   // 65.7 KB
  __shared__ int    gli[G_ * K_];        // 8 KB, this b's gather indices
  __shared__ float  ctab[K_];            // elliptic coeffs
  __shared__ float  red[16][64];         // per-wave partials

  const int tile = blockIdx.x;           // 0..31
  const int b    = blockIdx.y;           // 0..7
  const int t    = threadIdx.x;

  if (t < K_) ctab[t] = exp2f((float)t * (19.931568569324174f / 63.0f));

  gli[t]       = gidx[b * (G_ * K_) + t];
  gli[t + TPB] = gidx[b * (G_ * K_) + TPB + t];

  // ---- stage z = x - xopt as fp16, coalesced float4 ----
  {
    const float4* x4  = (const float4*)(x + ((size_t)(b * NP_ + tile * ROWS)) * D_);
    const float4* xo4 = (const float4*)(xopt + b * D_);
    const int col4 = t & 255;
    float4 xo = xo4[col4];
#pragma unroll
    for (int j = 0; j < (ROWS * 256) / TPB; ++j) {   // 8 iters
      int chunk = t + TPB * j;
      int row = chunk >> 8;
      float4 xv = x4[row * 256 + col4];
      __half2* p = (__half2*)(zh + row * STRIDE + col4 * 4);
      p[0] = __floats2half2_rn(xv.x - xo.x, xv.y - xo.y);
      p[1] = __floats2half2_rn(xv.z - xo.z, xv.w - xo.w);
    }
  }
  __syncthreads();

  const int wv   = t >> 6;               // 0..15  -> pair p = wv
  const int lane = t & 63;
  const int row  = lane & 31;
  const int h    = lane >> 5;
  const int cnt  = counts[b];

  float fit = 0.0f;

  if (2 * wv < cnt) {                    // wave-uniform gate; at cnt=32 all 16 waves busy
    const int g  = 2 * wv + h;           // may equal cnt when cnt odd -> weight 0 below
    const int bg = b * G_ + g;
    const __half* myrow = zh + row * STRIDE;
    const int*    gb    = gli + g * K_;  // 2 addrs/wave in LDS -> free

    float S[K_];
#pragma unroll
    for (int l = 0; l < K_; ++l) S[l] = 0.0f;

    // k-outer: S[l] += z_k * R[k][l]; R rows are wave-uniform -> s_load, branch-free
    for (int k = 0; k < K_; ++k) {
      int   gk = gb[k];
      float zk = __half2float(myrow[gk]);
      const float* rk = R + k * K_;
#pragma unroll
      for (int l = 0; l < K_; ++l) S[l] = fmaf(zk, rk[l], S[l]);
    }

    // epilogue: fit = sum_l wc[l] * S[l]^2, wc = w * coeff * mask (0 if g invalid)
    float wm = (g < cnt) ? weights[bg] : 0.0f;
    const int4* m4 = (const int4*)(mask + bg * K_);
#pragma unroll
    for (int q = 0; q < K_ / 4; ++q) {
      int4 mm = m4[q];
      float c0 = ctab[4 * q + 0], c1 = ctab[4 * q + 1];
      float c2 = ctab[4 * q + 2], c3 = ctab[4 * q + 3];
      float s0 = S[4 * q + 0], s1 = S[4 * q + 1];
      float s2 = S[4 * q + 2], s3 = S[4 * q + 3];
      fit = fmaf(mm.x ? wm * c0 : 0.0f, s0 * s0, fit);
      fit = fmaf(mm.y ? wm * c1 : 0.0f, s1 * s1, fit);
      fit = fmaf(mm.z ? wm * c2 : 0.0f, s2 * s2, fit);
      fit = fmaf(mm.w ? wm * c3 : 0.0f, s3 * s3, fit);
    }
  }

  red[wv][lane] = fit;
  __syncthreads();

  if (t < ROWS) {
    float s = 0.0f;
#pragma unroll
    for (int w2 = 0; w2 < 16; ++w2) s += red[w2][t] + red[w2][t + 32];
    out[b * NP_ + tile * ROWS + t] = s;
  }
}

extern "C" void kernel_launch(void* const* d_in, const int* in_sizes, int n_in,
                              void* d_out, int out_size, void* d_ws, size_t ws_size,
                              hipStream_t stream) {
  const float* x       = (const float*)d_in[0];   // (B,NP,D)
  const float* weights = (const float*)d_in[1];   // (B,G)
  const float* xopt    = (const float*)d_in[2];   // (B,D)
  const float* R       = (const float*)d_in[3];   // (K,K)
  const int*   gidx    = (const int*)d_in[4];     // (B,G,K)
  const int*   mask    = (const int*)d_in[5];     // (B,G,K) bool -> int32
  const int*   counts  = (const int*)d_in[6];     // (B,)
  float*       out     = (float*)d_out;           // (B,NP)

  fitness<<<dim3(NP_ / ROWS, B_), dim3(TPB), 0, stream>>>(
      x, weights, xopt, R, gidx, mask, counts, out);
}

// Round 5
// 90.167 us; speedup vs baseline: 1.6913x; 1.1917x over previous
//
#include <hip/hip_runtime.h>

typedef _Float16 half8  __attribute__((ext_vector_type(8)));
typedef _Float16 half4h __attribute__((ext_vector_type(4)));
typedef float    f32x4  __attribute__((ext_vector_type(4)));

#define B_     8
#define D_     1024
#define G_     32
#define K_     64
#define NP_    1024
#define ROWS   32
#define TPB    1024            // 16 waves
#define STRIDE 1028            // halfs per zh row: 8B-aligned rows, banks (2*row + idx/2)%32

__global__ __launch_bounds__(TPB) void fitness(
    const float* __restrict__ x,
    const float* __restrict__ weights,
    const float* __restrict__ xopt,
    const float* __restrict__ R,
    const int* __restrict__ gidx,
    const int* __restrict__ mask,     // numpy bool -> int32
    const int* __restrict__ counts,
    float* __restrict__ out) {
  __shared__ _Float16 zh[ROWS * STRIDE];   // 64.2 KB  z tile, fp16
  __shared__ int      gli[G_ * K_];        // 8 KB     gather indices for this b
  __shared__ _Float16 Rb[8 * 512];         // 8 KB     R in B-fragment order, fp16
  __shared__ float    wcs[G_ * K_];        // 8 KB     weight*coeff*mask (0 => dead)
  __shared__ float    redrow[ROWS];

  const int tile = blockIdx.x;             // 0..31
  const int b    = blockIdx.y;             // 0..7
  const int t    = threadIdx.x;
  const int cnt  = counts[b];

  // ---- stage gather indices ----
  gli[t]        = gidx[b * (G_ * K_) + t];
  gli[t + 1024] = gidx[b * (G_ * K_) + 1024 + t];

  // ---- stage wcs = weight * elliptic coeff * mask * group_valid ----
  {
    const float C = 19.931568569324174f / 63.0f;   // log2(1e6)/63
#pragma unroll
    for (int r = 0; r < 2; ++r) {
      int idx = t + r * 1024;
      int g = idx >> 6, l = idx & 63;
      bool v = (g < cnt) && (mask[b * (G_ * K_) + idx] != 0);
      wcs[idx] = v ? weights[b * G_ + g] * exp2f((float)l * C) : 0.0f;
    }
  }

  // ---- stage R in B-fragment order (fp16):
  //      Rb[frag*512 + lane*8 + j] = R[kt*32 + quad*8 + j][nt*16 + ln], frag = kt*4+nt
  {
    int pos  = t * 4;                      // 4 consecutive halves per thread
    int frag = pos >> 9, rem = pos & 511;
    int lane = rem >> 3, j0 = rem & 7;
    int kt = frag >> 2, nt = frag & 3;
    int quad = lane >> 4, ln = lane & 15;
    half4h rv;
#pragma unroll
    for (int e = 0; e < 4; ++e) {
      int k = kt * 32 + quad * 8 + j0 + e;
      rv[e] = (_Float16)R[k * K_ + nt * 16 + ln];
    }
    *(half4h*)(Rb + pos) = rv;
  }

  if (t < ROWS) redrow[t] = 0.0f;

  // ---- stage z = x - xopt as fp16, coalesced float4 ----
  {
    const float4* x4  = (const float4*)(x + ((size_t)(b * NP_ + tile * ROWS)) * D_);
    const float4* xo4 = (const float4*)(xopt + b * D_);
    const int col4 = t & 255;
    float4 xo = xo4[col4];
#pragma unroll
    for (int j = 0; j < (ROWS * 256) / TPB; ++j) {   // 8 iters
      int row = (t >> 8) + 4 * j;
      float4 xv = x4[row * 256 + col4];
      half4h hv;
      hv[0] = (_Float16)(xv.x - xo.x);
      hv[1] = (_Float16)(xv.y - xo.y);
      hv[2] = (_Float16)(xv.z - xo.z);
      hv[3] = (_Float16)(xv.w - xo.w);
      *(half4h*)(zh + row * STRIDE + col4 * 4) = hv;
    }
  }
  __syncthreads();

  // ---- MFMA compute: item = (g, mtile), g < cnt, mtile in {0,1} ----
  const int wv   = t >> 6;
  const int lane = t & 63;
  const int quad = lane >> 4;
  const int ln   = lane & 15;
  const int items = 2 * cnt;

  const half8* rbf = (const half8*)Rb;     // fragment f, lane: rbf[f*64 + lane]

  for (int i = wv; i < items; i += 16) {
    const int g     = i >> 1;
    const int mtile = i & 1;

    // A-fragments: A[m = ln][k = quad*8 + j] (+32 for kt=1), m120-verified layout
    const int* gp = gli + g * K_ + quad * 8;
    int4 i0 = *(const int4*)(gp);
    int4 i1 = *(const int4*)(gp + 4);
    int4 i2 = *(const int4*)(gp + 32);
    int4 i3 = *(const int4*)(gp + 36);
    const _Float16* zr = zh + (mtile * 16 + ln) * STRIDE;
    half8 a0, a1;
    a0[0] = zr[i0.x]; a0[1] = zr[i0.y]; a0[2] = zr[i0.z]; a0[3] = zr[i0.w];
    a0[4] = zr[i1.x]; a0[5] = zr[i1.y]; a0[6] = zr[i1.z]; a0[7] = zr[i1.w];
    a1[0] = zr[i2.x]; a1[1] = zr[i2.y]; a1[2] = zr[i2.z]; a1[3] = zr[i2.w];
    a1[4] = zr[i3.x]; a1[5] = zr[i3.y]; a1[6] = zr[i3.z]; a1[7] = zr[i3.w];

    f32x4 c0 = {0.f, 0.f, 0.f, 0.f}, c1 = c0, c2 = c0, c3 = c0;
    c0 = __builtin_amdgcn_mfma_f32_16x16x32_f16(a0, rbf[0 * 64 + lane], c0, 0, 0, 0);
    c1 = __builtin_amdgcn_mfma_f32_16x16x32_f16(a0, rbf[1 * 64 + lane], c1, 0, 0, 0);
    c2 = __builtin_amdgcn_mfma_f32_16x16x32_f16(a0, rbf[2 * 64 + lane], c2, 0, 0, 0);
    c3 = __builtin_amdgcn_mfma_f32_16x16x32_f16(a0, rbf[3 * 64 + lane], c3, 0, 0, 0);
    c0 = __builtin_amdgcn_mfma_f32_16x16x32_f16(a1, rbf[4 * 64 + lane], c0, 0, 0, 0);
    c1 = __builtin_amdgcn_mfma_f32_16x16x32_f16(a1, rbf[5 * 64 + lane], c1, 0, 0, 0);
    c2 = __builtin_amdgcn_mfma_f32_16x16x32_f16(a1, rbf[6 * 64 + lane], c2, 0, 0, 0);
    c3 = __builtin_amdgcn_mfma_f32_16x16x32_f16(a1, rbf[7 * 64 + lane], c3, 0, 0, 0);

    // epilogue: C[r] is row quad*4+r, col nt*16+ln (m89-verified C/D layout)
    const float* wg = wcs + g * K_ + ln;
    float w0 = wg[0], w1 = wg[16], w2 = wg[32], w3 = wg[48];
    float q0, q1, q2, q3;
    q0 = w0 * c0[0] * c0[0] + w1 * c1[0] * c1[0] + w2 * c2[0] * c2[0] + w3 * c3[0] * c3[0];
    q1 = w0 * c0[1] * c0[1] + w1 * c1[1] * c1[1] + w2 * c2[1] * c2[1] + w3 * c3[1] * c3[1];
    q2 = w0 * c0[2] * c0[2] + w1 * c1[2] * c1[2] + w2 * c2[2] * c2[2] + w3 * c3[2] * c3[2];
    q3 = w0 * c0[3] * c0[3] + w1 * c1[3] * c1[3] + w2 * c2[3] * c2[3] + w3 * c3[3] * c3[3];

    // reduce over the 16 lanes of each quad (cols), then one add per row
#pragma unroll
    for (int off = 1; off < 16; off <<= 1) {
      q0 += __shfl_xor(q0, off);
      q1 += __shfl_xor(q1, off);
      q2 += __shfl_xor(q2, off);
      q3 += __shfl_xor(q3, off);
    }
    if (ln == 0) {
      float* rr = redrow + mtile * 16 + quad * 4;
      atomicAdd(rr + 0, q0);
      atomicAdd(rr + 1, q1);
      atomicAdd(rr + 2, q2);
      atomicAdd(rr + 3, q3);
    }
  }
  __syncthreads();

  if (t < ROWS) out[b * NP_ + tile * ROWS + t] = redrow[t];
}

extern "C" void kernel_launch(void* const* d_in, const int* in_sizes, int n_in,
                              void* d_out, int out_size, void* d_ws, size_t ws_size,
                              hipStream_t stream) {
  const float* x       = (const float*)d_in[0];   // (B,NP,D)
  const float* weights = (const float*)d_in[1];   // (B,G)
  const float* xopt    = (const float*)d_in[2];   // (B,D)
  const float* R       = (const float*)d_in[3];   // (K,K)
  const int*   gidx    = (const int*)d_in[4];     // (B,G,K)
  const int*   mask    = (const int*)d_in[5];     // (B,G,K) bool -> int32
  const int*   counts  = (const int*)d_in[6];     // (B,)
  float*       out     = (float*)d_out;           // (B,NP)

  fitness<<<dim3(NP_ / ROWS, B_), dim3(TPB), 0, stream>>>(
      x, weights, xopt, R, gidx, mask, counts, out);
}

// Round 6
// 88.920 us; speedup vs baseline: 1.7150x; 1.0140x over previous
//
#include <hip/hip_runtime.h>

typedef _Float16 half8  __attribute__((ext_vector_type(8)));
typedef _Float16 half4h __attribute__((ext_vector_type(4)));
typedef float    f32x4  __attribute__((ext_vector_type(4)));

#define B_     8
#define D_     1024
#define G_     32
#define K_     64
#define NP_    1024
#define ROWS   16
#define TPB    512
#define STRIDE 1028            // halfs per zh row (rows 8B-aligned, 2-way banks = free)

// ws: wcs[B*G*K] floats (64 KB), then rbf[8*512] fp16 (8 KB, B-fragment order)

__global__ void prep(const float* __restrict__ weights,
                     const int* __restrict__ mask,
                     const int* __restrict__ counts,
                     const float* __restrict__ R,
                     float* __restrict__ wcs,
                     _Float16* __restrict__ rbf) {
  int idx = blockIdx.x * 256 + threadIdx.x;      // 0..16383
  int bg = idx >> 6, l = idx & 63;
  int b = bg >> 5, g = bg & 31;
  const float C = 19.931568569324174f / 63.0f;   // log2(1e6)/63
  bool v = (g < counts[b]) && (mask[idx] != 0);
  wcs[idx] = v ? weights[bg] * exp2f((float)l * C) : 0.0f;

  if (idx < 8 * 512) {                           // R -> B-fragment order, fp16
    int frag = idx >> 9, rem = idx & 511;
    int lane = rem >> 3, j = rem & 7;
    int kt = frag >> 2, nt = frag & 3;
    int quad = lane >> 4, ln = lane & 15;
    int k = kt * 32 + quad * 8 + j;
    rbf[idx] = (_Float16)R[k * K_ + nt * 16 + ln];
  }
}

__global__ __launch_bounds__(TPB, 4) void fitness(
    const float* __restrict__ x,
    const float* __restrict__ xopt,
    const int* __restrict__ gidx,
    const int* __restrict__ counts,
    const float* __restrict__ wcs,
    const _Float16* __restrict__ rbf,
    float* __restrict__ out) {
  __shared__ _Float16 zh[ROWS * STRIDE];   // 32.9 KB
  __shared__ int      gli[G_ * K_];        // 8 KB
  __shared__ float    redrow[ROWS];

  const int tile = blockIdx.x;             // 0..63
  const int b    = blockIdx.y;             // 0..7
  const int t    = threadIdx.x;
  const int cnt  = counts[b];

  // ---- stage gather indices (2048 ints, int4-vectorized) ----
  ((int4*)gli)[t] = ((const int4*)(gidx + b * (G_ * K_)))[t];
  if (t < ROWS) redrow[t] = 0.0f;

  // ---- stage z = x - xopt as fp16, coalesced float4 ----
  {
    const float4* x4  = (const float4*)(x + ((size_t)(b * NP_ + tile * ROWS)) * D_);
    const float4* xo4 = (const float4*)(xopt + b * D_);
    const int col4 = t & 255;
    float4 xo = xo4[col4];
#pragma unroll
    for (int j = 0; j < 8; ++j) {
      int row = (t >> 8) + 2 * j;
      float4 xv = x4[row * 256 + col4];
      half4h hv;
      hv[0] = (_Float16)(xv.x - xo.x);
      hv[1] = (_Float16)(xv.y - xo.y);
      hv[2] = (_Float16)(xv.z - xo.z);
      hv[3] = (_Float16)(xv.w - xo.w);
      *(half4h*)(zh + row * STRIDE + col4 * 4) = hv;
    }
  }

  const int wv   = t >> 6;                 // 0..7
  const int lane = t & 63;
  const int quad = lane >> 4;
  const int ln   = lane & 15;

  // R fragments: registers, once per wave (block-invariant)
  half8 rb[8];
#pragma unroll
  for (int f = 0; f < 8; ++f) rb[f] = *(const half8*)(rbf + f * 512 + lane * 8);

  __syncthreads();

  const _Float16* zr = zh + ln * STRIDE;   // this lane's z row (row = ln)
  float q0 = 0.f, q1 = 0.f, q2 = 0.f, q3 = 0.f;

  for (int g = wv; g < cnt; g += 8) {
    const float* wg = wcs + (b * G_ + g) * K_ + ln;   // issue L2 loads early
    float w0 = wg[0], w1 = wg[16], w2 = wg[32], w3 = wg[48];

    const int* gp = gli + g * K_ + quad * 8;
    int4 i0 = *(const int4*)(gp);
    int4 i1 = *(const int4*)(gp + 4);
    int4 i2 = *(const int4*)(gp + 32);
    int4 i3 = *(const int4*)(gp + 36);
    half8 a0, a1;
    a0[0] = zr[i0.x]; a0[1] = zr[i0.y]; a0[2] = zr[i0.z]; a0[3] = zr[i0.w];
    a0[4] = zr[i1.x]; a0[5] = zr[i1.y]; a0[6] = zr[i1.z]; a0[7] = zr[i1.w];
    a1[0] = zr[i2.x]; a1[1] = zr[i2.y]; a1[2] = zr[i2.z]; a1[3] = zr[i2.w];
    a1[4] = zr[i3.x]; a1[5] = zr[i3.y]; a1[6] = zr[i3.z]; a1[7] = zr[i3.w];

    f32x4 c0 = {0.f, 0.f, 0.f, 0.f}, c1 = c0, c2 = c0, c3 = c0;
    c0 = __builtin_amdgcn_mfma_f32_16x16x32_f16(a0, rb[0], c0, 0, 0, 0);
    c1 = __builtin_amdgcn_mfma_f32_16x16x32_f16(a0, rb[1], c1, 0, 0, 0);
    c2 = __builtin_amdgcn_mfma_f32_16x16x32_f16(a0, rb[2], c2, 0, 0, 0);
    c3 = __builtin_amdgcn_mfma_f32_16x16x32_f16(a0, rb[3], c3, 0, 0, 0);
    c0 = __builtin_amdgcn_mfma_f32_16x16x32_f16(a1, rb[4], c0, 0, 0, 0);
    c1 = __builtin_amdgcn_mfma_f32_16x16x32_f16(a1, rb[5], c1, 0, 0, 0);
    c2 = __builtin_amdgcn_mfma_f32_16x16x32_f16(a1, rb[6], c2, 0, 0, 0);
    c3 = __builtin_amdgcn_mfma_f32_16x16x32_f16(a1, rb[7], c3, 0, 0, 0);

    // C[r]: row quad*4+r (item-invariant), col nt*16+ln; accumulate w*S^2 per lane
    q0 += w0 * c0[0] * c0[0] + w1 * c1[0] * c1[0] + w2 * c2[0] * c2[0] + w3 * c3[0] * c3[0];
    q1 += w0 * c0[1] * c0[1] + w1 * c1[1] * c1[1] + w2 * c2[1] * c2[1] + w3 * c3[1] * c3[1];
    q2 += w0 * c0[2] * c0[2] + w1 * c1[2] * c1[2] + w2 * c2[2] * c2[2] + w3 * c3[2] * c3[2];
    q3 += w0 * c0[3] * c0[3] + w1 * c1[3] * c1[3] + w2 * c2[3] * c2[3] + w3 * c3[3] * c3[3];
  }

  // once per wave: reduce over the 16 cols (ln) — xor<16 stays within the quad
#pragma unroll
  for (int off = 1; off < 16; off <<= 1) {
    q0 += __shfl_xor(q0, off);
    q1 += __shfl_xor(q1, off);
    q2 += __shfl_xor(q2, off);
    q3 += __shfl_xor(q3, off);
  }
  if (ln == 0 && wv < cnt) {               // waves with no items contribute nothing
    float* rr = redrow + quad * 4;
    atomicAdd(rr + 0, q0);
    atomicAdd(rr + 1, q1);
    atomicAdd(rr + 2, q2);
    atomicAdd(rr + 3, q3);
  }
  __syncthreads();

  if (t < ROWS) out[b * NP_ + tile * ROWS + t] = redrow[t];
}

extern "C" void kernel_launch(void* const* d_in, const int* in_sizes, int n_in,
                              void* d_out, int out_size, void* d_ws, size_t ws_size,
                              hipStream_t stream) {
  const float* x       = (const float*)d_in[0];   // (B,NP,D)
  const float* weights = (const float*)d_in[1];   // (B,G)
  const float* xopt    = (const float*)d_in[2];   // (B,D)
  const float* R       = (const float*)d_in[3];   // (K,K)
  const int*   gidx    = (const int*)d_in[4];     // (B,G,K)
  const int*   mask    = (const int*)d_in[5];     // (B,G,K) bool -> int32
  const int*   counts  = (const int*)d_in[6];     // (B,)
  float*       out     = (float*)d_out;           // (B,NP)

  float*    wcs = (float*)d_ws;                   // 16384 floats
  _Float16* rbf = (_Float16*)((char*)d_ws + B_ * G_ * K_ * sizeof(float));

  prep<<<dim3(64), dim3(256), 0, stream>>>(weights, mask, counts, R, wcs, rbf);
  fitness<<<dim3(NP_ / ROWS, B_), dim3(TPB), 0, stream>>>(
      x, xopt, gidx, counts, wcs, rbf, out);
}

// Round 7
// 86.112 us; speedup vs baseline: 1.7710x; 1.0326x over previous
//
#include <hip/hip_runtime.h>

typedef _Float16 half8  __attribute__((ext_vector_type(8)));
typedef _Float16 half4h __attribute__((ext_vector_type(4)));
typedef float    f32x4  __attribute__((ext_vector_type(4)));

#define B_     8
#define D_     1024
#define G_     32
#define K_     64
#define NP_    1024
#define ROWS   16
#define TPB    512
#define STRIDE 1028            // halfs per zh row (rows 8B-aligned)

__global__ __launch_bounds__(TPB, 4) void fitness(
    const float* __restrict__ x,
    const float* __restrict__ weights,
    const float* __restrict__ xopt,
    const float* __restrict__ R,
    const int* __restrict__ gidx,
    const int* __restrict__ mask,     // numpy bool -> int32
    const int* __restrict__ counts,
    float* __restrict__ out) {
  __shared__ _Float16 zh[ROWS * STRIDE];   // 32.9 KB
  __shared__ int      gli[G_ * K_];        // 8 KB
  __shared__ _Float16 Rb[8 * 512];         // 8 KB, B-fragment order
  __shared__ float    ctab[K_];            // elliptic coeffs
  __shared__ float    redrow[ROWS];

  const int tile = blockIdx.x;             // 0..63
  const int b    = blockIdx.y;             // 0..7
  const int t    = threadIdx.x;
  const int cnt  = counts[b];

  // ---- stage gather indices (2048 ints via int4) ----
  ((int4*)gli)[t] = ((const int4*)(gidx + b * (G_ * K_)))[t];

  // ---- coeff table + reduction init ----
  if (t < K_) ctab[t] = exp2f((float)t * (19.931568569324174f / 63.0f));
  if (t < ROWS) redrow[t] = 0.0f;

  // ---- stage R -> B-fragment order fp16 (8 halfs per thread) ----
  {
    int pos  = t * 8;                      // 0..4095
    int frag = pos >> 9, rem = pos & 511;
    int lid  = rem >> 3;
    int kt = frag >> 2, nt = frag & 3;
    int quad = lid >> 4, ln = lid & 15;
    const float* rp = R + (kt * 32 + quad * 8) * K_ + nt * 16 + ln;
    half8 rv;
#pragma unroll
    for (int e = 0; e < 8; ++e) rv[e] = (_Float16)rp[e * K_];
    *(half8*)(Rb + pos) = rv;
  }

  // ---- stage z = x - xopt as fp16, coalesced float4 ----
  {
    const float4* x4  = (const float4*)(x + ((size_t)(b * NP_ + tile * ROWS)) * D_);
    const float4* xo4 = (const float4*)(xopt + b * D_);
    const int col4 = t & 255;
    float4 xo = xo4[col4];
#pragma unroll
    for (int j = 0; j < 8; ++j) {
      int row = (t >> 8) + 2 * j;
      float4 xv = x4[row * 256 + col4];
      half4h hv;
      hv[0] = (_Float16)(xv.x - xo.x);
      hv[1] = (_Float16)(xv.y - xo.y);
      hv[2] = (_Float16)(xv.z - xo.z);
      hv[3] = (_Float16)(xv.w - xo.w);
      *(half4h*)(zh + row * STRIDE + col4 * 4) = hv;
    }
  }
  __syncthreads();

  const int wv   = t >> 6;                 // 0..7
  const int lane = t & 63;
  const int quad = lane >> 4;
  const int ln   = lane & 15;

  // R fragments -> registers (block-invariant, ds_read_b128 x8)
  half8 rb[8];
#pragma unroll
  for (int f = 0; f < 8; ++f) rb[f] = *(const half8*)(Rb + f * 512 + lane * 8);

  // coeffs for this lane's 4 C-columns (l = nt*16 + ln)
  float cl0 = ctab[ln], cl1 = ctab[ln + 16], cl2 = ctab[ln + 32], cl3 = ctab[ln + 48];

  const _Float16* zr = zh + ln * STRIDE;   // this lane's z row (row = ln)
  float q0 = 0.f, q1 = 0.f, q2 = 0.f, q3 = 0.f;

  for (int g = wv; g < cnt; g += 8) {
    // prefetch epilogue operands (L2-hot, shared across all blocks)
    const int* mg = mask + (b * G_ + g) * K_ + ln;
    int   m0 = mg[0], m1 = mg[16], m2 = mg[32], m3 = mg[48];
    float w  = weights[b * G_ + g];

    const int* gp = gli + g * K_ + quad * 8;
    int4 i0 = *(const int4*)(gp);
    int4 i1 = *(const int4*)(gp + 4);
    int4 i2 = *(const int4*)(gp + 32);
    int4 i3 = *(const int4*)(gp + 36);
    half8 a0, a1;
    a0[0] = zr[i0.x]; a0[1] = zr[i0.y]; a0[2] = zr[i0.z]; a0[3] = zr[i0.w];
    a0[4] = zr[i1.x]; a0[5] = zr[i1.y]; a0[6] = zr[i1.z]; a0[7] = zr[i1.w];
    a1[0] = zr[i2.x]; a1[1] = zr[i2.y]; a1[2] = zr[i2.z]; a1[3] = zr[i2.w];
    a1[4] = zr[i3.x]; a1[5] = zr[i3.y]; a1[6] = zr[i3.z]; a1[7] = zr[i3.w];

    f32x4 c0 = {0.f, 0.f, 0.f, 0.f}, c1 = c0, c2 = c0, c3 = c0;
    c0 = __builtin_amdgcn_mfma_f32_16x16x32_f16(a0, rb[0], c0, 0, 0, 0);
    c1 = __builtin_amdgcn_mfma_f32_16x16x32_f16(a0, rb[1], c1, 0, 0, 0);
    c2 = __builtin_amdgcn_mfma_f32_16x16x32_f16(a0, rb[2], c2, 0, 0, 0);
    c3 = __builtin_amdgcn_mfma_f32_16x16x32_f16(a0, rb[3], c3, 0, 0, 0);
    c0 = __builtin_amdgcn_mfma_f32_16x16x32_f16(a1, rb[4], c0, 0, 0, 0);
    c1 = __builtin_amdgcn_mfma_f32_16x16x32_f16(a1, rb[5], c1, 0, 0, 0);
    c2 = __builtin_amdgcn_mfma_f32_16x16x32_f16(a1, rb[6], c2, 0, 0, 0);
    c3 = __builtin_amdgcn_mfma_f32_16x16x32_f16(a1, rb[7], c3, 0, 0, 0);

    float w0 = m0 ? w * cl0 : 0.0f;
    float w1 = m1 ? w * cl1 : 0.0f;
    float w2 = m2 ? w * cl2 : 0.0f;
    float w3 = m3 ? w * cl3 : 0.0f;

    // C[r]: row quad*4+r, col nt*16+ln; accumulate w*S^2 per lane across items
    q0 += w0 * c0[0] * c0[0] + w1 * c1[0] * c1[0] + w2 * c2[0] * c2[0] + w3 * c3[0] * c3[0];
    q1 += w0 * c0[1] * c0[1] + w1 * c1[1] * c1[1] + w2 * c2[1] * c2[1] + w3 * c3[1] * c3[1];
    q2 += w0 * c0[2] * c0[2] + w1 * c1[2] * c1[2] + w2 * c2[2] * c2[2] + w3 * c3[2] * c3[2];
    q3 += w0 * c0[3] * c0[3] + w1 * c1[3] * c1[3] + w2 * c2[3] * c2[3] + w3 * c3[3] * c3[3];
  }

  // reduce over the 16 cols (ln) once per wave; xor<16 stays within the quad
#pragma unroll
  for (int off = 1; off < 16; off <<= 1) {
    q0 += __shfl_xor(q0, off);
    q1 += __shfl_xor(q1, off);
    q2 += __shfl_xor(q2, off);
    q3 += __shfl_xor(q3, off);
  }
  if (ln == 0 && wv < cnt) {
    float* rr = redrow + quad * 4;
    atomicAdd(rr + 0, q0);
    atomicAdd(rr + 1, q1);
    atomicAdd(rr + 2, q2);
    atomicAdd(rr + 3, q3);
  }
  __syncthreads();

  if (t < ROWS) out[b * NP_ + tile * ROWS + t] = redrow[t];
}

extern "C" void kernel_launch(void* const* d_in, const int* in_sizes, int n_in,
                              void* d_out, int out_size, void* d_ws, size_t ws_size,
                              hipStream_t stream) {
  const float* x       = (const float*)d_in[0];   // (B,NP,D)
  const float* weights = (const float*)d_in[1];   // (B,G)
  const float* xopt    = (const float*)d_in[2];   // (B,D)
  const float* R       = (const float*)d_in[3];   // (K,K)
  const int*   gidx    = (const int*)d_in[4];     // (B,G,K)
  const int*   mask    = (const int*)d_in[5];     // (B,G,K) bool -> int32
  const int*   counts  = (const int*)d_in[6];     // (B,)
  float*       out     = (float*)d_out;           // (B,NP)

  fitness<<<dim3(NP_ / ROWS, B_), dim3(TPB), 0, stream>>>(
      x, weights, xopt, R, gidx, mask, counts, out);
}